// Round 1
// baseline (699.547 us; speedup 1.0000x reference)
//
#include <hip/hip_runtime.h>
#include <hip/hip_bf16.h>
#include <math.h>

// Problem constants
#define B_    32
#define CDD_  5
#define HIS_  100
#define S_    20
#define L_    3
#define F_    150
#define K_    18
#define RDIM_ 256
#define ROWE_ 9000           // S*L*F
#define NBC_  160            // B*CDD

// ---------------------------------------------------------------------------
// Kernel A: attention + stable top-K (grid=160 blocks of 64 = 1 wave)
// attn[b,c,h] = dot(repr[cdd_id[b,c]], repr[his_id[b,h]])  (fp32, deterministic
// per-h summation so duplicate his_ids give bit-equal values -> stable ties)
// Select K=18 in descending order, ties -> smaller h (matches stable argsort).
// Also zero-inits the score accumulator used by kernel D.
// ---------------------------------------------------------------------------
__global__ __launch_bounds__(64) void attn_topk_kernel(
    const int* __restrict__ cdd_id, const int* __restrict__ his_id,
    const float* __restrict__ repr, int* __restrict__ gid,
    float* __restrict__ score) {
  int bc = blockIdx.x;          // 0..159
  int b  = bc / CDD_;
  int lane = threadIdx.x;       // 0..63
  __shared__ float cddv[RDIM_];
  int cid = cdd_id[bc];
  for (int i = lane; i < RDIM_; i += 64)
    cddv[i] = repr[(size_t)cid * RDIM_ + i];
  __syncthreads();

  float v0 = -INFINITY, v1 = -INFINITY;
  {
    const float* row = repr + (size_t)his_id[b * HIS_ + lane] * RDIM_;
    float acc = 0.f;
    for (int r = 0; r < RDIM_; r++) acc = fmaf(cddv[r], row[r], acc);
    v0 = acc;
  }
  if (lane + 64 < HIS_) {
    const float* row = repr + (size_t)his_id[b * HIS_ + lane + 64] * RDIM_;
    float acc = 0.f;
    for (int r = 0; r < RDIM_; r++) acc = fmaf(cddv[r], row[r], acc);
    v1 = acc;
  }

  for (int k = 0; k < K_; k++) {
    float bv; int bi;
    if (v1 > v0) { bv = v1; bi = lane + 64; } else { bv = v0; bi = lane; }
    #pragma unroll
    for (int off = 32; off >= 1; off >>= 1) {
      float ov = __shfl_xor(bv, off);
      int   oi = __shfl_xor(bi, off);
      if (ov > bv || (ov == bv && oi < bi)) { bv = ov; bi = oi; }
    }
    if (lane == 0) gid[bc * K_ + k] = his_id[b * HIS_ + bi];
    if (bi == lane)      v0 = -INFINITY;
    if (bi == lane + 64) v1 = -INFINITY;
  }
  if (lane == 0) score[bc] = 0.f;
}

// ---------------------------------------------------------------------------
// Kernel B: fusion einsum. grid = 2880 blocks (b,c,k), 256 threads.
// fusion[l][s][t] = (1/sqrt(150)) * sum_f cddrow[s*450+l*150+f]*hisrow[t*450+l*150+f]
// his row staged in LDS (36KB); cdd row read via L1 (shared by the 18 k-blocks).
// Output written in conv1 input layout x1[n][l][k][s][t].
// ---------------------------------------------------------------------------
__global__ __launch_bounds__(256) void fusion_kernel(
    const int* __restrict__ cdd_id, const int* __restrict__ gid,
    const float* __restrict__ emb, float* __restrict__ x1) {
  int bck = blockIdx.x;
  int bc = bck / K_, k = bck % K_;
  __shared__ float hs[ROWE_];
  const float* crow = emb + (size_t)cdd_id[bc] * ROWE_;
  const float4* h4 = (const float4*)(emb + (size_t)gid[bck] * ROWE_);
  float4* hs4 = (float4*)hs;
  for (int i = threadIdx.x; i < ROWE_ / 4; i += 256) hs4[i] = h4[i];
  __syncthreads();

  const float scale = 0.0816496580927726f;  // 1/sqrt(150)
  for (int tile = threadIdx.x; tile < 300; tile += 256) {
    int l = tile / 100; int rem = tile % 100;
    int s0 = (rem / 10) * 2, t0 = (rem % 10) * 2;
    const float* c0 = crow + s0 * 450 + l * 150;
    const float* c1 = c0 + 450;
    const float* h0 = hs + t0 * 450 + l * 150;
    const float* h1 = h0 + 450;
    float a00 = 0, a01 = 0, a10 = 0, a11 = 0;
    for (int f = 0; f < F_; f += 2) {
      float2 ca = *(const float2*)(c0 + f);
      float2 cb = *(const float2*)(c1 + f);
      float2 ha = *(const float2*)(h0 + f);
      float2 hb = *(const float2*)(h1 + f);
      a00 = fmaf(ca.x, ha.x, a00); a00 = fmaf(ca.y, ha.y, a00);
      a01 = fmaf(ca.x, hb.x, a01); a01 = fmaf(ca.y, hb.y, a01);
      a10 = fmaf(cb.x, ha.x, a10); a10 = fmaf(cb.y, ha.y, a10);
      a11 = fmaf(cb.x, hb.x, a11); a11 = fmaf(cb.y, hb.y, a11);
    }
    size_t base = ((size_t)(bc * 3 + l) * K_ + k) * 400 + s0 * 20 + t0;
    x1[base]      = a00 * scale;
    x1[base + 1]  = a01 * scale;
    x1[base + 20] = a10 * scale;
    x1[base + 21] = a11 * scale;
  }
}

// ---------------------------------------------------------------------------
// Kernel C: conv1(3->32, 3x3x3, pad1) + bias + ReLU + maxpool 3x3x3/3, fused.
// grid = (n, dp) = 160*6 = 960 blocks, 256 threads.
// Only conv positions consumed by the pool (d,h,w in 18^3) are computed.
// Input tile (padded 3x5x22x22) in LDS; 81 inputs register-cached per position;
// weights read uniformly (scalar cache); pooling via LDS uint atomicMax.
// ---------------------------------------------------------------------------
__global__ __launch_bounds__(256) void conv1_kernel(
    const float* __restrict__ x1, const float* __restrict__ w1,
    const float* __restrict__ b1, float* __restrict__ p1) {
  int bid = blockIdx.x;
  int n = bid / 6, dp = bid % 6;
  __shared__ float tile[3 * 5 * 22 * 22];     // 7260 floats
  __shared__ unsigned pooled[32 * 36];        // 32 oc x (6x6)
  int tid = threadIdx.x;

  for (int i = tid; i < 7260; i += 256) {
    int c = i / 2420; int r = i % 2420;
    int dd = r / 484; r %= 484;
    int hh = r / 22, ww = r % 22;
    int d = dp * 3 + dd - 1, h = hh - 1, w = ww - 1;
    float v = 0.f;
    if (d >= 0 && d < 18 && h >= 0 && h < 20 && w >= 0 && w < 20)
      v = x1[((size_t)(n * 3 + c) * K_ + d) * 400 + h * 20 + w];
    tile[i] = v;
  }
  for (int i = tid; i < 1152; i += 256) pooled[i] = 0u;
  __syncthreads();

  for (int pos = tid; pos < 972; pos += 256) {
    int dl = pos / 324; int r = pos % 324;
    int h = r / 18, w = r % 18;
    float in[81];
    #pragma unroll
    for (int c = 0; c < 3; c++)
      #pragma unroll
      for (int kd = 0; kd < 3; kd++)
        #pragma unroll
        for (int kh = 0; kh < 3; kh++)
          #pragma unroll
          for (int kw = 0; kw < 3; kw++)
            in[((c * 3 + kd) * 3 + kh) * 3 + kw] =
                tile[((c * 5 + dl + kd) * 22 + h + kh) * 22 + w + kw];
    int pbase = (h / 3) * 6 + (w / 3);
    for (int oc = 0; oc < 32; oc++) {
      float acc = b1[oc];
      #pragma unroll
      for (int j = 0; j < 81; j++) acc = fmaf(in[j], w1[oc * 81 + j], acc);
      acc = fmaxf(acc, 0.f);
      atomicMax(&pooled[oc * 36 + pbase], __float_as_uint(acc));
    }
  }
  __syncthreads();
  for (int i = tid; i < 1152; i += 256) {
    int oc = i / 36; int r = i % 36;
    p1[(size_t)(n * 32 + oc) * 216 + dp * 36 + r] = __uint_as_float(pooled[i]);
  }
}

// ---------------------------------------------------------------------------
// Kernel D: conv2(32->16, 3x3x3, pad1) + bias + ReLU + maxpool 3^3/3 + LTR dot.
// grid = (n, oc-half) = 320 blocks, 256 threads (216 compute lanes).
// Input (32x216) staged unpadded in LDS (27KB); window loads bounds-checked.
// Each thread: one conv position, 8 output channels in registers.
// Partial score committed with one float atomicAdd (2 adds, commutative ->
// bit-deterministic).
// ---------------------------------------------------------------------------
__global__ __launch_bounds__(256) void conv2_kernel(
    const float* __restrict__ p1, const float* __restrict__ w2,
    const float* __restrict__ b2, const float* __restrict__ lw,
    float* __restrict__ score) {
  int bid = blockIdx.x;
  int n = bid / 2, og = bid % 2;
  __shared__ float tile[32 * 216];   // 27KB
  __shared__ unsigned pooled[64];    // 8 oc x 8 pooled pos
  int tid = threadIdx.x;

  for (int i = tid; i < 32 * 216; i += 256)
    tile[i] = p1[(size_t)n * 32 * 216 + i];
  if (tid < 64) pooled[tid] = 0u;
  __syncthreads();

  if (tid < 216) {
    int d = tid / 36; int r = tid % 36;
    int h = r / 6, w = r % 6;
    float acc[8];
    #pragma unroll
    for (int oc = 0; oc < 8; oc++) acc[oc] = b2[og * 8 + oc];
    for (int c = 0; c < 32; c++) {
      float win[27];
      #pragma unroll
      for (int kd = 0; kd < 3; kd++)
        #pragma unroll
        for (int kh = 0; kh < 3; kh++)
          #pragma unroll
          for (int kw = 0; kw < 3; kw++) {
            int dd = d + kd - 1, hh = h + kh - 1, ww = w + kw - 1;
            bool ok = (dd >= 0 && dd < 6 && hh >= 0 && hh < 6 && ww >= 0 && ww < 6);
            win[(kd * 3 + kh) * 3 + kw] =
                ok ? tile[c * 216 + dd * 36 + hh * 6 + ww] : 0.f;
          }
      #pragma unroll
      for (int oc = 0; oc < 8; oc++) {
        const float* wp = w2 + ((size_t)(og * 8 + oc) * 32 + c) * 27;
        #pragma unroll
        for (int j = 0; j < 27; j++) acc[oc] = fmaf(win[j], wp[j], acc[oc]);
      }
    }
    int pb = (d / 3) * 4 + (h / 3) * 2 + (w / 3);
    #pragma unroll
    for (int oc = 0; oc < 8; oc++)
      atomicMax(&pooled[oc * 8 + pb], __float_as_uint(fmaxf(acc[oc], 0.f)));
  }
  __syncthreads();

  if (tid < 64) {
    int oc = tid / 8, pb = tid % 8;
    float contrib = __uint_as_float(pooled[tid]) * lw[(og * 8 + oc) * 8 + pb];
    #pragma unroll
    for (int off = 32; off >= 1; off >>= 1) contrib += __shfl_xor(contrib, off);
    if (tid == 0) atomicAdd(&score[n], contrib);
  }
}

// ---------------------------------------------------------------------------
// Kernel E: +bias, log_softmax over the 5 candidates per batch row.
// ---------------------------------------------------------------------------
__global__ __launch_bounds__(64) void softmax_kernel(
    const float* __restrict__ score, const float* __restrict__ lb,
    float* __restrict__ out) {
  int b = threadIdx.x;
  if (b < B_) {
    float s[CDD_];
    float mx = -INFINITY;
    #pragma unroll
    for (int c = 0; c < CDD_; c++) {
      s[c] = score[b * CDD_ + c] + lb[0];
      mx = fmaxf(mx, s[c]);
    }
    float sum = 0.f;
    #pragma unroll
    for (int c = 0; c < CDD_; c++) sum += expf(s[c] - mx);
    float lse = mx + logf(sum);
    #pragma unroll
    for (int c = 0; c < CDD_; c++) out[b * CDD_ + c] = s[c] - lse;
  }
}

// ---------------------------------------------------------------------------
extern "C" void kernel_launch(void* const* d_in, const int* in_sizes, int n_in,
                              void* d_out, int out_size, void* d_ws, size_t ws_size,
                              hipStream_t stream) {
  const int*   cdd_id = (const int*)d_in[0];
  const int*   his_id = (const int*)d_in[1];
  const float* repr   = (const float*)d_in[2];
  const float* emb    = (const float*)d_in[3];
  const float* w1     = (const float*)d_in[4];
  const float* b1     = (const float*)d_in[5];
  const float* w2     = (const float*)d_in[6];
  const float* b2     = (const float*)d_in[7];
  const float* lw     = (const float*)d_in[8];
  const float* lb     = (const float*)d_in[9];
  float* out = (float*)d_out;

  // workspace layout (total ~17.4 MB)
  char* ws = (char*)d_ws;
  int*   gid   = (int*)ws;                              // 2880 ints
  float* score = (float*)(ws + 11520);                  // 160 floats
  float* x1    = (float*)(ws + 12160);                  // 3,456,000 floats
  float* p1    = (float*)(ws + 12160 + 13824000);       // 1,105,920 floats

  attn_topk_kernel<<<NBC_, 64, 0, stream>>>(cdd_id, his_id, repr, gid, score);
  fusion_kernel<<<NBC_ * K_, 256, 0, stream>>>(cdd_id, gid, emb, x1);
  conv1_kernel<<<NBC_ * 6, 256, 0, stream>>>(x1, w1, b1, p1);
  conv2_kernel<<<NBC_ * 2, 256, 0, stream>>>(p1, w2, b2, lw, score);
  softmax_kernel<<<1, 64, 0, stream>>>(score, lb, out);
}

// Round 2
// 623.492 us; speedup vs baseline: 1.1220x; 1.1220x over previous
//
#include <hip/hip_runtime.h>
#include <hip/hip_bf16.h>
#include <math.h>

// Problem constants
#define B_    32
#define CDD_  5
#define HIS_  100
#define S_    20
#define L_    3
#define F_    150
#define K_    18
#define RDIM_ 256
#define ROWE_ 9000           // S*L*F
#define NBC_  160            // B*CDD

// ---------------------------------------------------------------------------
// Kernel P: transpose conv weights for scalar-broadcast access.
// w1t[j][oc]  (j = c*27+kd*9+kh*3+kw, 81 x 32)
// w2t[c*27+j][oc]  (864 x 16)
// ---------------------------------------------------------------------------
__global__ __launch_bounds__(256) void prep_kernel(
    const float* __restrict__ w1, const float* __restrict__ w2,
    float* __restrict__ w1t, float* __restrict__ w2t) {
  int tid = blockIdx.x * 256 + threadIdx.x;
  if (tid < 32 * 81) {
    int oc = tid / 81, j = tid % 81;
    w1t[j * 32 + oc] = w1[tid];
  }
  if (tid < 16 * 864) {
    int oc = tid / 864, r = tid % 864;
    w2t[r * 16 + oc] = w2[tid];
  }
}

// ---------------------------------------------------------------------------
// Kernel A: attention + stable top-K. grid=160 blocks x 256 threads.
// Wave-parallel dots: lane i holds float4 at offset 4i of each row ->
// fully coalesced 1KB-per-instruction loads; butterfly reduction is
// deterministic per row, so duplicate his_ids give bit-equal attn ->
// ties broken by smaller h (matches stable argsort).
// ---------------------------------------------------------------------------
__global__ __launch_bounds__(256) void attn_topk_kernel(
    const int* __restrict__ cdd_id, const int* __restrict__ his_id,
    const float* __restrict__ repr, int* __restrict__ gid,
    float* __restrict__ score) {
  int bc = blockIdx.x;          // 0..159
  int b  = bc / CDD_;
  int tid = threadIdx.x, lane = tid & 63, wave = tid >> 6;
  __shared__ float cddv[RDIM_];
  __shared__ float sattn[128];
  int cid = cdd_id[bc];
  cddv[tid] = repr[(size_t)cid * RDIM_ + tid];
  if (tid < 28) sattn[100 + tid] = -INFINITY;
  __syncthreads();

  float4 cv = *(const float4*)(cddv + lane * 4);
  for (int h = wave; h < HIS_; h += 4) {
    const float4* row = (const float4*)(repr + (size_t)his_id[b * HIS_ + h] * RDIM_);
    float4 rv = row[lane];
    float p = cv.x * rv.x;
    p = fmaf(cv.y, rv.y, p);
    p = fmaf(cv.z, rv.z, p);
    p = fmaf(cv.w, rv.w, p);
    #pragma unroll
    for (int off = 32; off >= 1; off >>= 1) p += __shfl_xor(p, off);
    if (lane == 0) sattn[h] = p;
  }
  __syncthreads();

  if (wave == 0) {
    float v0 = sattn[lane], v1 = sattn[lane + 64];
    for (int k = 0; k < K_; k++) {
      float bv; int bi;
      if (v1 > v0) { bv = v1; bi = lane + 64; } else { bv = v0; bi = lane; }
      #pragma unroll
      for (int off = 32; off >= 1; off >>= 1) {
        float ov = __shfl_xor(bv, off);
        int   oi = __shfl_xor(bi, off);
        if (ov > bv || (ov == bv && oi < bi)) { bv = ov; bi = oi; }
      }
      if (lane == 0) gid[bc * K_ + k] = his_id[b * HIS_ + bi];
      if (bi == lane)      v0 = -INFINITY;
      if (bi == lane + 64) v1 = -INFINITY;
    }
  }
  if (tid == 0) score[bc] = 0.f;
}

// ---------------------------------------------------------------------------
// Kernel B: fusion einsum. grid = 2880 blocks (b,c,k), 256 threads.
// (unchanged from round 1 for attribution)
// ---------------------------------------------------------------------------
__global__ __launch_bounds__(256) void fusion_kernel(
    const int* __restrict__ cdd_id, const int* __restrict__ gid,
    const float* __restrict__ emb, float* __restrict__ x1) {
  int bck = blockIdx.x;
  int bc = bck / K_, k = bck % K_;
  __shared__ float hs[ROWE_];
  const float* crow = emb + (size_t)cdd_id[bc] * ROWE_;
  const float4* h4 = (const float4*)(emb + (size_t)gid[bck] * ROWE_);
  float4* hs4 = (float4*)hs;
  for (int i = threadIdx.x; i < ROWE_ / 4; i += 256) hs4[i] = h4[i];
  __syncthreads();

  const float scale = 0.0816496580927726f;  // 1/sqrt(150)
  for (int tile = threadIdx.x; tile < 300; tile += 256) {
    int l = tile / 100; int rem = tile % 100;
    int s0 = (rem / 10) * 2, t0 = (rem % 10) * 2;
    const float* c0 = crow + s0 * 450 + l * 150;
    const float* c1 = c0 + 450;
    const float* h0 = hs + t0 * 450 + l * 150;
    const float* h1 = h0 + 450;
    float a00 = 0, a01 = 0, a10 = 0, a11 = 0;
    for (int f = 0; f < F_; f += 2) {
      float2 ca = *(const float2*)(c0 + f);
      float2 cb = *(const float2*)(c1 + f);
      float2 ha = *(const float2*)(h0 + f);
      float2 hb = *(const float2*)(h1 + f);
      a00 = fmaf(ca.x, ha.x, a00); a00 = fmaf(ca.y, ha.y, a00);
      a01 = fmaf(ca.x, hb.x, a01); a01 = fmaf(ca.y, hb.y, a01);
      a10 = fmaf(cb.x, ha.x, a10); a10 = fmaf(cb.y, ha.y, a10);
      a11 = fmaf(cb.x, hb.x, a11); a11 = fmaf(cb.y, hb.y, a11);
    }
    size_t base = ((size_t)(bc * 3 + l) * K_ + k) * 400 + s0 * 20 + t0;
    x1[base]      = a00 * scale;
    x1[base + 1]  = a01 * scale;
    x1[base + 20] = a10 * scale;
    x1[base + 21] = a11 * scale;
  }
}

// ---------------------------------------------------------------------------
// Kernel C: conv1(3->32) + bias + ReLU + maxpool, fused. grid = 960, 256 thr.
// Restructured: thread=position with acc[32] in registers (low VGPR, no
// spill); inner loop = 1 LDS input read -> 32 FMAs against w1t[j][0..31]
// which is wave-uniform -> scalar cache (s_load_dwordx8), no VMEM cost.
// ---------------------------------------------------------------------------
__global__ __launch_bounds__(256) void conv1_kernel(
    const float* __restrict__ x1, const float* __restrict__ w1t,
    const float* __restrict__ b1, float* __restrict__ p1) {
  int bid = blockIdx.x;
  int n = bid / 6, dp = bid % 6;
  __shared__ float tile[3 * 5 * 22 * 22];     // 7260 floats, padded input slab
  __shared__ unsigned pooled[32 * 36];        // 32 oc x (6x6)
  int tid = threadIdx.x;

  for (int i = tid; i < 7260; i += 256) {
    int c = i / 2420; int r = i % 2420;
    int dd = r / 484; r %= 484;
    int hh = r / 22, ww = r % 22;
    int d = dp * 3 + dd - 1, h = hh - 1, w = ww - 1;
    float v = 0.f;
    if (d >= 0 && d < 18 && h >= 0 && h < 20 && w >= 0 && w < 20)
      v = x1[((size_t)(n * 3 + c) * K_ + d) * 400 + h * 20 + w];
    tile[i] = v;
  }
  for (int i = tid; i < 1152; i += 256) pooled[i] = 0u;
  __syncthreads();

  for (int pos = tid; pos < 972; pos += 256) {
    int dl = pos / 324; int r = pos % 324;
    int h = r / 18, w = r % 18;
    float acc[32];
    #pragma unroll
    for (int oc = 0; oc < 32; oc++) acc[oc] = b1[oc];

    for (int c = 0; c < 3; c++) {
      const float* tc = tile + (c * 5 + dl) * 484 + h * 22 + w;
      const float* wc = w1t + c * 27 * 32;
      #pragma unroll
      for (int kd = 0; kd < 3; kd++)
        #pragma unroll
        for (int kh = 0; kh < 3; kh++)
          #pragma unroll
          for (int kw = 0; kw < 3; kw++) {
            float iv = tc[kd * 484 + kh * 22 + kw];
            const float* wp = wc + (kd * 9 + kh * 3 + kw) * 32;
            #pragma unroll
            for (int oc = 0; oc < 32; oc++) acc[oc] = fmaf(iv, wp[oc], acc[oc]);
          }
    }
    int pbase = (h / 3) * 6 + (w / 3);
    #pragma unroll
    for (int oc = 0; oc < 32; oc++)
      atomicMax(&pooled[oc * 36 + pbase], __float_as_uint(fmaxf(acc[oc], 0.f)));
  }
  __syncthreads();
  for (int i = tid; i < 1152; i += 256) {
    int oc = i / 36; int r = i % 36;
    p1[(size_t)(n * 32 + oc) * 216 + dp * 36 + r] = __uint_as_float(pooled[i]);
  }
}

// ---------------------------------------------------------------------------
// Kernel D: conv2(32->16) + bias + ReLU + maxpool + LTR dot. grid = 320.
// Padded LDS tile [32][8][8][8] removes all bounds checks; acc[8] registers;
// scalar-broadcast weights from w2t. One float atomicAdd per block into
// score[n] (2 commutative adds -> deterministic).
// ---------------------------------------------------------------------------
__global__ __launch_bounds__(256) void conv2_kernel(
    const float* __restrict__ p1, const float* __restrict__ w2t,
    const float* __restrict__ b2, const float* __restrict__ lw,
    float* __restrict__ score) {
  int bid = blockIdx.x;
  int n = bid / 2, og = bid % 2;
  __shared__ float tile[32 * 8 * 8 * 8];   // 64KB padded: [c][d+1][h+1][w+1]
  __shared__ unsigned pooled[64];          // 8 oc x 8 pooled pos
  int tid = threadIdx.x;

  for (int i = tid; i < 32 * 512; i += 256) tile[i] = 0.f;
  if (tid < 64) pooled[tid] = 0u;
  __syncthreads();
  for (int i = tid; i < 32 * 216; i += 256) {
    int c = i / 216; int r = i % 216;
    int d = r / 36; r %= 36;
    int h = r / 6, w = r % 6;
    tile[c * 512 + (d + 1) * 64 + (h + 1) * 8 + (w + 1)] =
        p1[(size_t)n * 32 * 216 + i];
  }
  __syncthreads();

  if (tid < 216) {
    int d = tid / 36; int r = tid % 36;
    int h = r / 6, w = r % 6;
    float acc[8];
    #pragma unroll
    for (int oc = 0; oc < 8; oc++) acc[oc] = b2[og * 8 + oc];
    for (int c = 0; c < 32; c++) {
      const float* tc = tile + c * 512 + d * 64 + h * 8 + w;  // window origin
      const float* wc = w2t + c * 27 * 16 + og * 8;
      #pragma unroll
      for (int kd = 0; kd < 3; kd++)
        #pragma unroll
        for (int kh = 0; kh < 3; kh++)
          #pragma unroll
          for (int kw = 0; kw < 3; kw++) {
            float iv = tc[kd * 64 + kh * 8 + kw];
            const float* wp = wc + (kd * 9 + kh * 3 + kw) * 16;
            #pragma unroll
            for (int oc = 0; oc < 8; oc++) acc[oc] = fmaf(iv, wp[oc], acc[oc]);
          }
    }
    int pb = (d / 3) * 4 + (h / 3) * 2 + (w / 3);
    #pragma unroll
    for (int oc = 0; oc < 8; oc++)
      atomicMax(&pooled[oc * 8 + pb], __float_as_uint(fmaxf(acc[oc], 0.f)));
  }
  __syncthreads();

  if (tid < 64) {
    int oc = tid / 8, pb = tid % 8;
    float contrib = __uint_as_float(pooled[tid]) * lw[(og * 8 + oc) * 8 + pb];
    #pragma unroll
    for (int off = 32; off >= 1; off >>= 1) contrib += __shfl_xor(contrib, off);
    if (tid == 0) atomicAdd(&score[n], contrib);
  }
}

// ---------------------------------------------------------------------------
// Kernel E: +bias, log_softmax over the 5 candidates per batch row.
// ---------------------------------------------------------------------------
__global__ __launch_bounds__(64) void softmax_kernel(
    const float* __restrict__ score, const float* __restrict__ lb,
    float* __restrict__ out) {
  int b = threadIdx.x;
  if (b < B_) {
    float s[CDD_];
    float mx = -INFINITY;
    #pragma unroll
    for (int c = 0; c < CDD_; c++) {
      s[c] = score[b * CDD_ + c] + lb[0];
      mx = fmaxf(mx, s[c]);
    }
    float sum = 0.f;
    #pragma unroll
    for (int c = 0; c < CDD_; c++) sum += expf(s[c] - mx);
    float lse = mx + logf(sum);
    #pragma unroll
    for (int c = 0; c < CDD_; c++) out[b * CDD_ + c] = s[c] - lse;
  }
}

// ---------------------------------------------------------------------------
extern "C" void kernel_launch(void* const* d_in, const int* in_sizes, int n_in,
                              void* d_out, int out_size, void* d_ws, size_t ws_size,
                              hipStream_t stream) {
  const int*   cdd_id = (const int*)d_in[0];
  const int*   his_id = (const int*)d_in[1];
  const float* repr   = (const float*)d_in[2];
  const float* emb    = (const float*)d_in[3];
  const float* w1     = (const float*)d_in[4];
  const float* b1     = (const float*)d_in[5];
  const float* w2     = (const float*)d_in[6];
  const float* b2     = (const float*)d_in[7];
  const float* lw     = (const float*)d_in[8];
  const float* lb     = (const float*)d_in[9];
  float* out = (float*)d_out;

  // workspace layout (~18.3 MB)
  char* ws = (char*)d_ws;
  int*   gid   = (int*)ws;                               // 2880 ints
  float* score = (float*)(ws + 11520);                   // 160 floats
  float* x1    = (float*)(ws + 12160);                   // 3,456,000 floats
  float* p1    = (float*)(ws + 12160 + 13824000);        // 1,105,920 floats
  float* w1t   = (float*)(ws + 12160 + 13824000 + 4423680);        // 2592 f
  float* w2t   = (float*)(ws + 12160 + 13824000 + 4423680 + 10368); // 13824 f

  prep_kernel<<<54, 256, 0, stream>>>(w1, w2, w1t, w2t);
  attn_topk_kernel<<<NBC_, 256, 0, stream>>>(cdd_id, his_id, repr, gid, score);
  fusion_kernel<<<NBC_ * K_, 256, 0, stream>>>(cdd_id, gid, emb, x1);
  conv1_kernel<<<NBC_ * 6, 256, 0, stream>>>(x1, w1t, b1, p1);
  conv2_kernel<<<NBC_ * 2, 256, 0, stream>>>(p1, w2t, b2, lw, score);
  softmax_kernel<<<1, 64, 0, stream>>>(score, lb, out);
}

// Round 3
// 613.006 us; speedup vs baseline: 1.1412x; 1.0171x over previous
//
#include <hip/hip_runtime.h>
#include <hip/hip_bf16.h>
#include <math.h>

// Problem constants
#define B_    32
#define CDD_  5
#define HIS_  100
#define S_    20
#define L_    3
#define F_    150
#define K_    18
#define RDIM_ 256
#define ROWE_ 9000           // S*L*F
#define NBC_  160            // B*CDD

typedef __attribute__((ext_vector_type(8))) short short8;
typedef __attribute__((ext_vector_type(4))) float f32x4;

// RNE float->bf16 (no NaN inputs here)
static __device__ __forceinline__ unsigned short f2bf(float x) {
  union { float f; unsigned u; } v; v.f = x;
  unsigned r = v.u + 0x7fffu + ((v.u >> 16) & 1u);
  return (unsigned short)(r >> 16);
}

// ---------------------------------------------------------------------------
// Kernel A: attention + stable top-K. grid=160 blocks x 256 threads.
// Also performs the conv-weight transposes (prep duty folded in) and
// zero-inits the score accumulator.
// ---------------------------------------------------------------------------
__global__ __launch_bounds__(256) void attn_topk_kernel(
    const int* __restrict__ cdd_id, const int* __restrict__ his_id,
    const float* __restrict__ repr, int* __restrict__ gid,
    float* __restrict__ score,
    const float* __restrict__ w1, const float* __restrict__ w2,
    float* __restrict__ w1t, float* __restrict__ w2t) {
  int bc = blockIdx.x;          // 0..159
  int b  = bc / CDD_;
  int tid = threadIdx.x, lane = tid & 63, wave = tid >> 6;

  // prep duty: weight transposes, distributed over the grid
  int gidx = bc * 256 + tid;
  if (gidx < 2592) {
    int oc = gidx / 81, j = gidx % 81;
    w1t[j * 32 + oc] = w1[gidx];
  } else if (gidx < 2592 + 13824) {
    int i2 = gidx - 2592;
    int oc = i2 / 864, r = i2 % 864;
    w2t[r * 16 + oc] = w2[i2];
  }

  __shared__ float cddv[RDIM_];
  __shared__ float sattn[128];
  int cid = cdd_id[bc];
  cddv[tid] = repr[(size_t)cid * RDIM_ + tid];
  if (tid < 28) sattn[100 + tid] = -INFINITY;
  __syncthreads();

  float4 cv = *(const float4*)(cddv + lane * 4);
  for (int h = wave; h < HIS_; h += 4) {
    const float4* row = (const float4*)(repr + (size_t)his_id[b * HIS_ + h] * RDIM_);
    float4 rv = row[lane];
    float p = cv.x * rv.x;
    p = fmaf(cv.y, rv.y, p);
    p = fmaf(cv.z, rv.z, p);
    p = fmaf(cv.w, rv.w, p);
    #pragma unroll
    for (int off = 32; off >= 1; off >>= 1) p += __shfl_xor(p, off);
    if (lane == 0) sattn[h] = p;
  }
  __syncthreads();

  if (wave == 0) {
    float v0 = sattn[lane], v1 = sattn[lane + 64];
    for (int k = 0; k < K_; k++) {
      float bv; int bi;
      if (v1 > v0) { bv = v1; bi = lane + 64; } else { bv = v0; bi = lane; }
      #pragma unroll
      for (int off = 32; off >= 1; off >>= 1) {
        float ov = __shfl_xor(bv, off);
        int   oi = __shfl_xor(bi, off);
        if (ov > bv || (ov == bv && oi < bi)) { bv = ov; bi = oi; }
      }
      if (lane == 0) gid[bc * K_ + k] = his_id[b * HIS_ + bi];
      if (bi == lane)      v0 = -INFINITY;
      if (bi == lane + 64) v1 = -INFINITY;
    }
  }
  if (tid == 0) score[bc] = 0.f;
}

// ---------------------------------------------------------------------------
// Kernel B: fusion einsum via bf16 MFMA. grid = 2880 blocks (b,c,k), 256 thr.
// Per l: C[20x20] = A[20x150] x B[20x150]^T, as 2x2 tiles of 16x16 with
// 5 K-steps of 32 (K padded 150->160, M/N padded 20->32 with zeros).
// Both operands are K-major so A and B fragments load identically:
// frag[m=lane&15][k=(lane>>4)*8+j] = contiguous 16B -> ds_read_b128.
// C/D: col=lane&15, row=(lane>>4)*4+reg (verified layout).
// ---------------------------------------------------------------------------
__global__ __launch_bounds__(256) void fusion_kernel(
    const int* __restrict__ cdd_id, const int* __restrict__ gid,
    const float* __restrict__ emb, float* __restrict__ x1) {
  int bck = blockIdx.x;
  int bc = bck / K_, k = bck % K_;
  __shared__ unsigned short a_sh[3 * 32 * 160];   // 30 KB
  __shared__ unsigned short b_sh[3 * 32 * 160];   // 30 KB
  int tid = threadIdx.x;

  unsigned* az = (unsigned*)a_sh;
  unsigned* bz = (unsigned*)b_sh;
  for (int i = tid; i < 3 * 32 * 80; i += 256) { az[i] = 0u; bz[i] = 0u; }
  __syncthreads();

  const float* crow = emb + (size_t)cdd_id[bc] * ROWE_;
  const float* hrow = emb + (size_t)gid[bck] * ROWE_;
  for (int p = tid; p < 4500; p += 256) {     // pairs of f
    int s = p / 225, r = p % 225;
    int l = r / 75, f2 = r % 75;
    int src = s * 450 + l * 150 + 2 * f2;
    float2 cv = *(const float2*)(crow + src);
    float2 hv = *(const float2*)(hrow + src);
    int dst = (l * 32 + s) * 80 + f2;         // uint index
    az[dst] = (unsigned)f2bf(cv.x) | ((unsigned)f2bf(cv.y) << 16);
    bz[dst] = (unsigned)f2bf(hv.x) | ((unsigned)f2bf(hv.y) << 16);
  }
  __syncthreads();

  int wave = tid >> 6, lane = tid & 63;
  int m15 = lane & 15, quad = lane >> 4;
  const float scale = 0.0816496580927726f;    // 1/sqrt(150)
  for (int j = wave; j < 12; j += 4) {        // j = l*4 + mt*2 + nt
    int l = j >> 2, mt = (j >> 1) & 1, nt = j & 1;
    f32x4 acc = {0.f, 0.f, 0.f, 0.f};
    int abase = (l * 32 + mt * 16 + m15) * 160 + quad * 8;
    int bbase = (l * 32 + nt * 16 + m15) * 160 + quad * 8;
    #pragma unroll
    for (int kb = 0; kb < 5; kb++) {
      short8 af = *(const short8*)(a_sh + abase + kb * 32);
      short8 bf = *(const short8*)(b_sh + bbase + kb * 32);
      acc = __builtin_amdgcn_mfma_f32_16x16x32_bf16(af, bf, acc, 0, 0, 0);
    }
    int t = nt * 16 + m15;
    if (t < 20) {
      size_t base = ((size_t)(bc * 3 + l) * K_ + k) * 400;
      #pragma unroll
      for (int reg = 0; reg < 4; reg++) {
        int s = mt * 16 + quad * 4 + reg;
        if (s < 20) x1[base + s * 20 + t] = acc[reg] * scale;
      }
    }
  }
}

// ---------------------------------------------------------------------------
// Kernel C: conv1(3->32) + bias + ReLU + maxpool, fused. grid = 960, 256 thr.
// Thread=position, acc[32] registers; inner loop = 1 LDS read broadcast into
// 32 FMAs with scalar-cached weights from w1t.
// ---------------------------------------------------------------------------
__global__ __launch_bounds__(256) void conv1_kernel(
    const float* __restrict__ x1, const float* __restrict__ w1t,
    const float* __restrict__ b1, float* __restrict__ p1) {
  int bid = blockIdx.x;
  int n = bid / 6, dp = bid % 6;
  __shared__ float tile[3 * 5 * 22 * 22];     // 7260 floats, padded input slab
  __shared__ unsigned pooled[32 * 36];        // 32 oc x (6x6)
  int tid = threadIdx.x;

  for (int i = tid; i < 7260; i += 256) {
    int c = i / 2420; int r = i % 2420;
    int dd = r / 484; r %= 484;
    int hh = r / 22, ww = r % 22;
    int d = dp * 3 + dd - 1, h = hh - 1, w = ww - 1;
    float v = 0.f;
    if (d >= 0 && d < 18 && h >= 0 && h < 20 && w >= 0 && w < 20)
      v = x1[((size_t)(n * 3 + c) * K_ + d) * 400 + h * 20 + w];
    tile[i] = v;
  }
  for (int i = tid; i < 1152; i += 256) pooled[i] = 0u;
  __syncthreads();

  for (int pos = tid; pos < 972; pos += 256) {
    int dl = pos / 324; int r = pos % 324;
    int h = r / 18, w = r % 18;
    float acc[32];
    #pragma unroll
    for (int oc = 0; oc < 32; oc++) acc[oc] = b1[oc];

    for (int c = 0; c < 3; c++) {
      const float* tc = tile + (c * 5 + dl) * 484 + h * 22 + w;
      const float* wc = w1t + c * 27 * 32;
      #pragma unroll
      for (int kd = 0; kd < 3; kd++)
        #pragma unroll
        for (int kh = 0; kh < 3; kh++)
          #pragma unroll
          for (int kw = 0; kw < 3; kw++) {
            float iv = tc[kd * 484 + kh * 22 + kw];
            const float* wp = wc + (kd * 9 + kh * 3 + kw) * 32;
            #pragma unroll
            for (int oc = 0; oc < 32; oc++) acc[oc] = fmaf(iv, wp[oc], acc[oc]);
          }
    }
    int pbase = (h / 3) * 6 + (w / 3);
    #pragma unroll
    for (int oc = 0; oc < 32; oc++)
      atomicMax(&pooled[oc * 36 + pbase], __float_as_uint(fmaxf(acc[oc], 0.f)));
  }
  __syncthreads();
  for (int i = tid; i < 1152; i += 256) {
    int oc = i / 36; int r = i % 36;
    p1[(size_t)(n * 32 + oc) * 216 + dp * 36 + r] = __uint_as_float(pooled[i]);
  }
}

// ---------------------------------------------------------------------------
// Kernel D: conv2(32->16) + bias + ReLU + maxpool + LTR dot. grid = 320.
// Padded LDS tile [32][8][8][8]; acc[8] registers; scalar-broadcast weights.
// One float atomicAdd per block into score[n].
// ---------------------------------------------------------------------------
__global__ __launch_bounds__(256) void conv2_kernel(
    const float* __restrict__ p1, const float* __restrict__ w2t,
    const float* __restrict__ b2, const float* __restrict__ lw,
    float* __restrict__ score) {
  int bid = blockIdx.x;
  int n = bid / 2, og = bid % 2;
  __shared__ float tile[32 * 8 * 8 * 8];   // 64KB padded: [c][d+1][h+1][w+1]
  __shared__ unsigned pooled[64];          // 8 oc x 8 pooled pos
  int tid = threadIdx.x;

  for (int i = tid; i < 32 * 512; i += 256) tile[i] = 0.f;
  if (tid < 64) pooled[tid] = 0u;
  __syncthreads();
  for (int i = tid; i < 32 * 216; i += 256) {
    int c = i / 216; int r = i % 216;
    int d = r / 36; r %= 36;
    int h = r / 6, w = r % 6;
    tile[c * 512 + (d + 1) * 64 + (h + 1) * 8 + (w + 1)] =
        p1[(size_t)n * 32 * 216 + i];
  }
  __syncthreads();

  if (tid < 216) {
    int d = tid / 36; int r = tid % 36;
    int h = r / 6, w = r % 6;
    float acc[8];
    #pragma unroll
    for (int oc = 0; oc < 8; oc++) acc[oc] = b2[og * 8 + oc];
    for (int c = 0; c < 32; c++) {
      const float* tc = tile + c * 512 + d * 64 + h * 8 + w;  // window origin
      const float* wc = w2t + c * 27 * 16 + og * 8;
      #pragma unroll
      for (int kd = 0; kd < 3; kd++)
        #pragma unroll
        for (int kh = 0; kh < 3; kh++)
          #pragma unroll
          for (int kw = 0; kw < 3; kw++) {
            float iv = tc[kd * 64 + kh * 8 + kw];
            const float* wp = wc + (kd * 9 + kh * 3 + kw) * 16;
            #pragma unroll
            for (int oc = 0; oc < 8; oc++) acc[oc] = fmaf(iv, wp[oc], acc[oc]);
          }
    }
    int pb = (d / 3) * 4 + (h / 3) * 2 + (w / 3);
    #pragma unroll
    for (int oc = 0; oc < 8; oc++)
      atomicMax(&pooled[oc * 8 + pb], __float_as_uint(fmaxf(acc[oc], 0.f)));
  }
  __syncthreads();

  if (tid < 64) {
    int oc = tid / 8, pb = tid % 8;
    float contrib = __uint_as_float(pooled[tid]) * lw[(og * 8 + oc) * 8 + pb];
    #pragma unroll
    for (int off = 32; off >= 1; off >>= 1) contrib += __shfl_xor(contrib, off);
    if (tid == 0) atomicAdd(&score[n], contrib);
  }
}

// ---------------------------------------------------------------------------
// Kernel E: +bias, log_softmax over the 5 candidates per batch row.
// ---------------------------------------------------------------------------
__global__ __launch_bounds__(64) void softmax_kernel(
    const float* __restrict__ score, const float* __restrict__ lb,
    float* __restrict__ out) {
  int b = threadIdx.x;
  if (b < B_) {
    float s[CDD_];
    float mx = -INFINITY;
    #pragma unroll
    for (int c = 0; c < CDD_; c++) {
      s[c] = score[b * CDD_ + c] + lb[0];
      mx = fmaxf(mx, s[c]);
    }
    float sum = 0.f;
    #pragma unroll
    for (int c = 0; c < CDD_; c++) sum += expf(s[c] - mx);
    float lse = mx + logf(sum);
    #pragma unroll
    for (int c = 0; c < CDD_; c++) out[b * CDD_ + c] = s[c] - lse;
  }
}

// ---------------------------------------------------------------------------
extern "C" void kernel_launch(void* const* d_in, const int* in_sizes, int n_in,
                              void* d_out, int out_size, void* d_ws, size_t ws_size,
                              hipStream_t stream) {
  const int*   cdd_id = (const int*)d_in[0];
  const int*   his_id = (const int*)d_in[1];
  const float* repr   = (const float*)d_in[2];
  const float* emb    = (const float*)d_in[3];
  const float* w1     = (const float*)d_in[4];
  const float* b1     = (const float*)d_in[5];
  const float* w2     = (const float*)d_in[6];
  const float* b2     = (const float*)d_in[7];
  const float* lw     = (const float*)d_in[8];
  const float* lb     = (const float*)d_in[9];
  float* out = (float*)d_out;

  // workspace layout (~18.3 MB)
  char* ws = (char*)d_ws;
  int*   gid   = (int*)ws;                               // 2880 ints
  float* score = (float*)(ws + 11520);                   // 160 floats
  float* x1    = (float*)(ws + 12160);                   // 3,456,000 floats
  float* p1    = (float*)(ws + 12160 + 13824000);        // 1,105,920 floats
  float* w1t   = (float*)(ws + 12160 + 13824000 + 4423680);        // 2592 f
  float* w2t   = (float*)(ws + 12160 + 13824000 + 4423680 + 10368); // 13824 f

  attn_topk_kernel<<<NBC_, 256, 0, stream>>>(cdd_id, his_id, repr, gid, score,
                                             w1, w2, w1t, w2t);
  fusion_kernel<<<NBC_ * K_, 256, 0, stream>>>(cdd_id, gid, emb, x1);
  conv1_kernel<<<NBC_ * 6, 256, 0, stream>>>(x1, w1t, b1, p1);
  conv2_kernel<<<NBC_ * 2, 256, 0, stream>>>(p1, w2t, b2, lw, score);
  softmax_kernel<<<1, 64, 0, stream>>>(score, lb, out);
}